// Round 1
// baseline (1035.107 us; speedup 1.0000x reference)
//
#include <hip/hip_runtime.h>
#include <hip/hip_bf16.h>

#define B_  16
#define TQ_ 1024
#define TK_ 4096
#define D_  512

#define BM 128
#define BN 128
#define BK 32
#define PAD 40   // bf16 elems per LDS row: 80B stride = 20 banks -> 2-way (free), 16B aligned

typedef unsigned short u16;
typedef __attribute__((ext_vector_type(8))) short short8;   // 8 bf16 (4 VGPRs) - verified frag type
typedef __attribute__((ext_vector_type(4))) float f32x4;

__device__ __forceinline__ u16 bf16_rne(float x) {
  unsigned u = __float_as_uint(x);
  u += 0x7FFFu + ((u >> 16) & 1u);
  return (u16)(u >> 16);
}
__device__ __forceinline__ float bf16_as_f32(u16 h) {
  return __uint_as_float(((unsigned)h) << 16);
}
__device__ __forceinline__ void split_f32(float x, u16& h, u16& l) {
  u16 hh = bf16_rne(x);
  h = hh;
  l = bf16_rne(x - bf16_as_f32(hh));
}

// ---------------------------------------------------------------------------
// enc [b][k][d] fp32  ->  encT [b][d][k] bf16
// ---------------------------------------------------------------------------
__global__ __launch_bounds__(256) void transpose_conv_kernel(
    const float* __restrict__ E, u16* __restrict__ ET)
{
  __shared__ float tile[64][65];
  const int b  = blockIdx.z;
  const int k0 = blockIdx.x * 64;
  const int d0 = blockIdx.y * 64;
  const float* Eb = E + (long long)b * TK_ * D_;
  u16* ETb = ET + (long long)b * D_ * TK_;

  const int t  = threadIdx.x;
  const int r  = t >> 2;          // 0..63
  const int c4 = (t & 3) * 16;    // 0,16,32,48

  #pragma unroll
  for (int i = 0; i < 16; i += 4) {
    float4 v = *(const float4*)&Eb[(long long)(k0 + r) * D_ + d0 + c4 + i];
    tile[r][c4 + i + 0] = v.x;
    tile[r][c4 + i + 1] = v.y;
    tile[r][c4 + i + 2] = v.z;
    tile[r][c4 + i + 3] = v.w;
  }
  __syncthreads();

  __align__(16) u16 h[16];
  #pragma unroll
  for (int i = 0; i < 16; ++i) h[i] = bf16_rne(tile[c4 + i][r]);
  uint4* dst = (uint4*)&ETb[(long long)(d0 + r) * TK_ + k0 + c4];
  dst[0] = ((const uint4*)h)[0];
  dst[1] = ((const uint4*)h)[1];
}

// ---------------------------------------------------------------------------
// Split-precision GEMM: C[M,N] = A[M,K] * B[N,K]^T   (A,B fp32, C fp32)
// fp32 ~ hi + lo (bf16 each); C += Ah*Bh + Ah*Bl + Al*Bh  (error ~2^-18)
// ---------------------------------------------------------------------------
__global__ __launch_bounds__(256) void gemm_split_kernel(
    const float* __restrict__ A, const float* __restrict__ Bm,
    float* __restrict__ C,
    int K, int ldc,
    long long sA, long long sB, long long sC)
{
  __shared__ u16 Ah[BM * PAD];
  __shared__ u16 Al[BM * PAD];
  __shared__ u16 Bh[BN * PAD];
  __shared__ u16 Bl[BN * PAD];

  const int bz = blockIdx.z;
  const float* Ab = A  + (long long)bz * sA + (long long)(blockIdx.y * BM) * K;
  const float* Bb = Bm + (long long)bz * sB + (long long)(blockIdx.x * BN) * K;

  const int t    = threadIdx.x;
  const int r    = t >> 1;        // 0..127
  const int hf   = t & 1;         // col half (16 floats each)
  const int lane = t & 63;
  const int wave = t >> 6;
  const int wr   = (wave >> 1) * 64;
  const int wc   = (wave & 1) * 64;
  const int ln   = lane & 15;
  const int qd   = lane >> 4;

  f32x4 acc[4][4];
  #pragma unroll
  for (int i = 0; i < 4; ++i)
    #pragma unroll
    for (int j = 0; j < 4; ++j) { f32x4 z = {0.f,0.f,0.f,0.f}; acc[i][j] = z; }

  const float* srcA = Ab + (long long)r * K + hf * 16;
  const float* srcB = Bb + (long long)r * K + hf * 16;
  u16* dAh = &Ah[r * PAD + hf * 16];
  u16* dAl = &Al[r * PAD + hf * 16];
  u16* dBh = &Bh[r * PAD + hf * 16];
  u16* dBl = &Bl[r * PAD + hf * 16];

  for (int k0 = 0; k0 < K; k0 += BK) {
    {
      __align__(16) u16 h[16], l[16];
      #pragma unroll
      for (int i = 0; i < 16; i += 4) {
        float4 v = *(const float4*)(srcA + k0 + i);
        split_f32(v.x, h[i+0], l[i+0]);
        split_f32(v.y, h[i+1], l[i+1]);
        split_f32(v.z, h[i+2], l[i+2]);
        split_f32(v.w, h[i+3], l[i+3]);
      }
      ((uint4*)dAh)[0] = ((const uint4*)h)[0];
      ((uint4*)dAh)[1] = ((const uint4*)h)[1];
      ((uint4*)dAl)[0] = ((const uint4*)l)[0];
      ((uint4*)dAl)[1] = ((const uint4*)l)[1];
      #pragma unroll
      for (int i = 0; i < 16; i += 4) {
        float4 v = *(const float4*)(srcB + k0 + i);
        split_f32(v.x, h[i+0], l[i+0]);
        split_f32(v.y, h[i+1], l[i+1]);
        split_f32(v.z, h[i+2], l[i+2]);
        split_f32(v.w, h[i+3], l[i+3]);
      }
      ((uint4*)dBh)[0] = ((const uint4*)h)[0];
      ((uint4*)dBh)[1] = ((const uint4*)h)[1];
      ((uint4*)dBl)[0] = ((const uint4*)l)[0];
      ((uint4*)dBl)[1] = ((const uint4*)l)[1];
    }
    __syncthreads();

    short8 fah[4], fal[4], fbh[4], fbl[4];
    #pragma unroll
    for (int i = 0; i < 4; ++i) {
      int ra = (wr + i * 16 + ln) * PAD + qd * 8;
      int rb = (wc + i * 16 + ln) * PAD + qd * 8;
      fah[i] = *(const short8*)&Ah[ra];
      fal[i] = *(const short8*)&Al[ra];
      fbh[i] = *(const short8*)&Bh[rb];
      fbl[i] = *(const short8*)&Bl[rb];
    }
    #pragma unroll
    for (int i = 0; i < 4; ++i)
      #pragma unroll
      for (int j = 0; j < 4; ++j) {
        acc[i][j] = __builtin_amdgcn_mfma_f32_16x16x32_bf16(fah[i], fbh[j], acc[i][j], 0, 0, 0);
        acc[i][j] = __builtin_amdgcn_mfma_f32_16x16x32_bf16(fah[i], fbl[j], acc[i][j], 0, 0, 0);
        acc[i][j] = __builtin_amdgcn_mfma_f32_16x16x32_bf16(fal[i], fbh[j], acc[i][j], 0, 0, 0);
      }
    __syncthreads();
  }

  float* Cb = C + (long long)bz * sC;
  const int m0 = blockIdx.y * BM;
  const int n0 = blockIdx.x * BN;
  #pragma unroll
  for (int i = 0; i < 4; ++i)
    #pragma unroll
    for (int j = 0; j < 4; ++j)
      #pragma unroll
      for (int rg = 0; rg < 4; ++rg) {
        int row = m0 + wr + i * 16 + qd * 4 + rg;   // C/D: row = quad*4 + reg
        int col = n0 + wc + j * 16 + ln;            // C/D: col = lane&15
        Cb[(long long)row * ldc + col] = acc[i][j][rg];
      }
}

// ---------------------------------------------------------------------------
// Row softmax in place: P is [B*TQ, TK] fp32
// ---------------------------------------------------------------------------
__global__ __launch_bounds__(256) void softmax_kernel(float* __restrict__ P)
{
  __shared__ float red[8];
  float* p = P + (long long)blockIdx.x * TK_;
  const int t    = threadIdx.x;
  const int lane = t & 63;
  const int wave = t >> 6;

  float4 v[4];
  float mx = -3.0e38f;
  #pragma unroll
  for (int i = 0; i < 4; ++i) {
    v[i] = *(const float4*)&p[i * 1024 + t * 4];
    mx = fmaxf(mx, fmaxf(fmaxf(v[i].x, v[i].y), fmaxf(v[i].z, v[i].w)));
  }
  #pragma unroll
  for (int o = 32; o > 0; o >>= 1) mx = fmaxf(mx, __shfl_xor(mx, o, 64));
  if (lane == 0) red[wave] = mx;
  __syncthreads();
  mx = fmaxf(fmaxf(red[0], red[1]), fmaxf(red[2], red[3]));

  float s = 0.f;
  #pragma unroll
  for (int i = 0; i < 4; ++i) {
    v[i].x = __expf(v[i].x - mx);
    v[i].y = __expf(v[i].y - mx);
    v[i].z = __expf(v[i].z - mx);
    v[i].w = __expf(v[i].w - mx);
    s += (v[i].x + v[i].y) + (v[i].z + v[i].w);
  }
  #pragma unroll
  for (int o = 32; o > 0; o >>= 1) s += __shfl_xor(s, o, 64);
  if (lane == 0) red[4 + wave] = s;
  __syncthreads();
  s = (red[4] + red[5]) + (red[6] + red[7]);
  const float inv = 1.0f / s;

  #pragma unroll
  for (int i = 0; i < 4; ++i) {
    v[i].x *= inv; v[i].y *= inv; v[i].z *= inv; v[i].w *= inv;
    *(float4*)&p[i * 1024 + t * 4] = v[i];
  }
}

// ---------------------------------------------------------------------------
// Context GEMM (plain bf16): C[1024,512] = P[1024,4096] * encT[512,4096]^T
// A staged fp32->bf16(hi); B already bf16 K-contiguous.
// ---------------------------------------------------------------------------
__global__ __launch_bounds__(256) void gemm_ctx_kernel(
    const float* __restrict__ P, const u16* __restrict__ ET,
    float* __restrict__ C)
{
  __shared__ u16 Ahs[BM * PAD];
  __shared__ u16 Bhs[BN * PAD];

  const int bz = blockIdx.z;
  const float* Pb = P  + (long long)bz * TQ_ * TK_ + (long long)(blockIdx.y * BM) * TK_;
  const u16*   Eb = ET + (long long)bz * D_ * TK_  + (long long)(blockIdx.x * BN) * TK_;

  const int t    = threadIdx.x;
  const int r    = t >> 1;
  const int hf   = t & 1;
  const int lane = t & 63;
  const int wave = t >> 6;
  const int wr   = (wave >> 1) * 64;
  const int wc   = (wave & 1) * 64;
  const int ln   = lane & 15;
  const int qd   = lane >> 4;

  f32x4 acc[4][4];
  #pragma unroll
  for (int i = 0; i < 4; ++i)
    #pragma unroll
    for (int j = 0; j < 4; ++j) { f32x4 z = {0.f,0.f,0.f,0.f}; acc[i][j] = z; }

  const float* srcA = Pb + (long long)r * TK_ + hf * 16;
  const u16*   srcB = Eb + (long long)r * TK_ + hf * 16;
  u16* dA = &Ahs[r * PAD + hf * 16];
  u16* dB = &Bhs[r * PAD + hf * 16];

  for (int k0 = 0; k0 < TK_; k0 += BK) {
    {
      __align__(16) u16 h[16];
      #pragma unroll
      for (int i = 0; i < 16; i += 4) {
        float4 v = *(const float4*)(srcA + k0 + i);
        h[i+0] = bf16_rne(v.x);
        h[i+1] = bf16_rne(v.y);
        h[i+2] = bf16_rne(v.z);
        h[i+3] = bf16_rne(v.w);
      }
      ((uint4*)dA)[0] = ((const uint4*)h)[0];
      ((uint4*)dA)[1] = ((const uint4*)h)[1];
      const uint4* sb = (const uint4*)(srcB + k0);
      ((uint4*)dB)[0] = sb[0];
      ((uint4*)dB)[1] = sb[1];
    }
    __syncthreads();

    short8 fa[4], fb[4];
    #pragma unroll
    for (int i = 0; i < 4; ++i) {
      fa[i] = *(const short8*)&Ahs[(wr + i * 16 + ln) * PAD + qd * 8];
      fb[i] = *(const short8*)&Bhs[(wc + i * 16 + ln) * PAD + qd * 8];
    }
    #pragma unroll
    for (int i = 0; i < 4; ++i)
      #pragma unroll
      for (int j = 0; j < 4; ++j)
        acc[i][j] = __builtin_amdgcn_mfma_f32_16x16x32_bf16(fa[i], fb[j], acc[i][j], 0, 0, 0);
    __syncthreads();
  }

  float* Cb = C + (long long)bz * TQ_ * D_;
  const int m0 = blockIdx.y * BM;
  const int n0 = blockIdx.x * BN;
  #pragma unroll
  for (int i = 0; i < 4; ++i)
    #pragma unroll
    for (int j = 0; j < 4; ++j)
      #pragma unroll
      for (int rg = 0; rg < 4; ++rg) {
        int row = m0 + wr + i * 16 + qd * 4 + rg;
        int col = n0 + wc + j * 16 + ln;
        Cb[(long long)row * D_ + col] = acc[i][j][rg];
      }
}

// ---------------------------------------------------------------------------
extern "C" void kernel_launch(void* const* d_in, const int* in_sizes, int n_in,
                              void* d_out, int out_size, void* d_ws, size_t ws_size,
                              hipStream_t stream) {
  (void)in_sizes; (void)n_in; (void)out_size; (void)ws_size;
  const float* dec = (const float*)d_in[0];   // [16,1024,512]
  const float* enc = (const float*)d_in[1];   // [16,4096,512]
  const float* Wa  = (const float*)d_in[2];   // [512,512]
  // d_in[3] = b_a: constant along softmax axis -> cancels exactly; unused.

  float* ctx   = (float*)d_out;                                   // [16,1024,512]
  float* align = ctx + (long long)B_ * TQ_ * D_;                  // [16,1024,4096]

  float* dec2 = (float*)d_ws;                                     // 33.5 MB fp32
  u16*   encT = (u16*)((char*)d_ws + sizeof(float) * (size_t)B_ * TQ_ * D_); // 67 MB bf16

  // 1) encT[b][d][k] = bf16(enc[b][k][d])
  transpose_conv_kernel<<<dim3(TK_ / 64, D_ / 64, B_), 256, 0, stream>>>(enc, encT);

  // 2) dec2[q][d] = sum_e dec[q][e] * W[d][e]   (split precision)
  gemm_split_kernel<<<dim3(D_ / BN, (B_ * TQ_) / BM, 1), 256, 0, stream>>>(
      dec, Wa, dec2, D_, D_, 0, 0, 0);

  // 3) score[b][q][k] = sum_d dec2[b][q][d] * enc[b][k][d]  (split precision)
  gemm_split_kernel<<<dim3(TK_ / BN, TQ_ / BM, B_), 256, 0, stream>>>(
      dec2, enc, align, D_, TK_,
      (long long)TQ_ * D_, (long long)TK_ * D_, (long long)TQ_ * TK_);

  // 4) softmax rows in place
  softmax_kernel<<<B_ * TQ_, 256, 0, stream>>>(align);

  // 5) ctx[b][q][d] = sum_k align[b][q][k] * encT[b][d][k]  (plain bf16)
  gemm_ctx_kernel<<<dim3(D_ / BN, TQ_ / BM, B_), 256, 0, stream>>>(align, encT, ctx);
}

// Round 2
// 891.547 us; speedup vs baseline: 1.1610x; 1.1610x over previous
//
#include <hip/hip_runtime.h>
#include <hip/hip_bf16.h>

#define B_  16
#define TQ_ 1024
#define TK_ 4096
#define D_  512

typedef unsigned short u16;
typedef __attribute__((ext_vector_type(8))) short short8;      // 8 bf16
typedef __attribute__((ext_vector_type(8))) _Float16 f16x8;    // 8 f16 (4 VGPRs)
typedef __attribute__((ext_vector_type(4))) float f32x4;

__device__ __forceinline__ u16 bf16_rne(float x) {
  unsigned u = __float_as_uint(x);
  u += 0x7FFFu + ((u >> 16) & 1u);
  return (u16)(u >> 16);
}
__device__ __forceinline__ float bf16_as_f32(u16 h) {
  return __uint_as_float(((unsigned)h) << 16);
}
__device__ __forceinline__ void split_bf16(float x, u16& h, u16& l) {
  u16 hh = bf16_rne(x);
  h = hh;
  l = bf16_rne(x - bf16_as_f32(hh));
}

// async global->LDS, 16B per lane; LDS dest must be wave-contiguous (base + lane*16)
__device__ __forceinline__ void glld16(const void* g, void* lds) {
  __builtin_amdgcn_global_load_lds(
      (const __attribute__((address_space(1))) unsigned int*)g,
      (__attribute__((address_space(3))) unsigned int*)lds, 16, 0, 0);
}

// ---------------------------------------------------------------------------
// enc [b][k][d] fp32  ->  encT [b][d][k] f16
// ---------------------------------------------------------------------------
__global__ __launch_bounds__(256) void transpose_conv_kernel(
    const float* __restrict__ E, _Float16* __restrict__ ET)
{
  __shared__ float tile[64][65];
  const int b  = blockIdx.z;
  const int k0 = blockIdx.x * 64;
  const int d0 = blockIdx.y * 64;
  const float* Eb = E + (long long)b * TK_ * D_;
  _Float16* ETb = ET + (long long)b * D_ * TK_;

  const int t  = threadIdx.x;
  const int r  = t >> 2;          // 0..63
  const int c4 = (t & 3) * 16;    // 0,16,32,48

  #pragma unroll
  for (int i = 0; i < 16; i += 4) {
    float4 v = *(const float4*)&Eb[(long long)(k0 + r) * D_ + d0 + c4 + i];
    tile[r][c4 + i + 0] = v.x;
    tile[r][c4 + i + 1] = v.y;
    tile[r][c4 + i + 2] = v.z;
    tile[r][c4 + i + 3] = v.w;
  }
  __syncthreads();

  __align__(16) _Float16 h[16];
  #pragma unroll
  for (int i = 0; i < 16; ++i) h[i] = (_Float16)tile[c4 + i][r];
  uint4* dst = (uint4*)&ETb[(long long)(d0 + r) * TK_ + k0 + c4];
  dst[0] = ((const uint4*)h)[0];
  dst[1] = ((const uint4*)h)[1];
}

// ---------------------------------------------------------------------------
// dec2 = dec @ W^T  (split-bf16 triple, R1-proven), epilogue emits f16 hi/lo
// A = dec [16384,512] fp32, B = W [512,512] fp32 (row n = W[n][:])
// ---------------------------------------------------------------------------
#define DBM 128
#define DBN 128
#define DBK 32
#define DPAD 40

__global__ __launch_bounds__(256) void gemm_dec2_kernel(
    const float* __restrict__ A, const float* __restrict__ Bm,
    _Float16* __restrict__ Ch, _Float16* __restrict__ Cl)
{
  __shared__ u16 Ah[DBM * DPAD];
  __shared__ u16 Al[DBM * DPAD];
  __shared__ u16 Bh[DBN * DPAD];
  __shared__ u16 Bl[DBN * DPAD];

  const float* Ab = A  + (long long)(blockIdx.y * DBM) * D_;
  const float* Bb = Bm + (long long)(blockIdx.x * DBN) * D_;

  const int t    = threadIdx.x;
  const int r    = t >> 1;
  const int hf   = t & 1;
  const int lane = t & 63;
  const int wave = t >> 6;
  const int wr   = (wave >> 1) * 64;
  const int wc   = (wave & 1) * 64;
  const int ln   = lane & 15;
  const int qd   = lane >> 4;

  f32x4 acc[4][4];
  #pragma unroll
  for (int i = 0; i < 4; ++i)
    #pragma unroll
    for (int j = 0; j < 4; ++j) { f32x4 z = {0.f,0.f,0.f,0.f}; acc[i][j] = z; }

  const float* srcA = Ab + (long long)r * D_ + hf * 16;
  const float* srcB = Bb + (long long)r * D_ + hf * 16;
  u16* dAh = &Ah[r * DPAD + hf * 16];
  u16* dAl = &Al[r * DPAD + hf * 16];
  u16* dBh = &Bh[r * DPAD + hf * 16];
  u16* dBl = &Bl[r * DPAD + hf * 16];

  for (int k0 = 0; k0 < D_; k0 += DBK) {
    {
      __align__(16) u16 h[16], l[16];
      #pragma unroll
      for (int i = 0; i < 16; i += 4) {
        float4 v = *(const float4*)(srcA + k0 + i);
        split_bf16(v.x, h[i+0], l[i+0]);
        split_bf16(v.y, h[i+1], l[i+1]);
        split_bf16(v.z, h[i+2], l[i+2]);
        split_bf16(v.w, h[i+3], l[i+3]);
      }
      ((uint4*)dAh)[0] = ((const uint4*)h)[0];
      ((uint4*)dAh)[1] = ((const uint4*)h)[1];
      ((uint4*)dAl)[0] = ((const uint4*)l)[0];
      ((uint4*)dAl)[1] = ((const uint4*)l)[1];
      #pragma unroll
      for (int i = 0; i < 16; i += 4) {
        float4 v = *(const float4*)(srcB + k0 + i);
        split_bf16(v.x, h[i+0], l[i+0]);
        split_bf16(v.y, h[i+1], l[i+1]);
        split_bf16(v.z, h[i+2], l[i+2]);
        split_bf16(v.w, h[i+3], l[i+3]);
      }
      ((uint4*)dBh)[0] = ((const uint4*)h)[0];
      ((uint4*)dBh)[1] = ((const uint4*)h)[1];
      ((uint4*)dBl)[0] = ((const uint4*)l)[0];
      ((uint4*)dBl)[1] = ((const uint4*)l)[1];
    }
    __syncthreads();

    short8 fah[4], fal[4], fbh[4], fbl[4];
    #pragma unroll
    for (int i = 0; i < 4; ++i) {
      int ra = (wr + i * 16 + ln) * DPAD + qd * 8;
      int rb = (wc + i * 16 + ln) * DPAD + qd * 8;
      fah[i] = *(const short8*)&Ah[ra];
      fal[i] = *(const short8*)&Al[ra];
      fbh[i] = *(const short8*)&Bh[rb];
      fbl[i] = *(const short8*)&Bl[rb];
    }
    #pragma unroll
    for (int i = 0; i < 4; ++i)
      #pragma unroll
      for (int j = 0; j < 4; ++j) {
        acc[i][j] = __builtin_amdgcn_mfma_f32_16x16x32_bf16(fah[i], fbh[j], acc[i][j], 0, 0, 0);
        acc[i][j] = __builtin_amdgcn_mfma_f32_16x16x32_bf16(fah[i], fbl[j], acc[i][j], 0, 0, 0);
        acc[i][j] = __builtin_amdgcn_mfma_f32_16x16x32_bf16(fal[i], fbh[j], acc[i][j], 0, 0, 0);
      }
    __syncthreads();
  }

  const int m0 = blockIdx.y * DBM;
  const int n0 = blockIdx.x * DBN;
  #pragma unroll
  for (int i = 0; i < 4; ++i)
    #pragma unroll
    for (int j = 0; j < 4; ++j)
      #pragma unroll
      for (int rg = 0; rg < 4; ++rg) {
        int row = m0 + wr + i * 16 + qd * 4 + rg;
        int col = n0 + wc + j * 16 + ln;
        float x = acc[i][j][rg];
        _Float16 h = (_Float16)x;
        _Float16 l = (_Float16)(x - (float)h);
        long long idx = (long long)row * D_ + col;
        Ch[idx] = h;
        Cl[idx] = l;
      }
}

// ---------------------------------------------------------------------------
// Score GEMM: C[b][q][k] = sum_d dec2[b,q,d] * enc[b,k,d]
// A = dec2 hi/lo f16 planes (glld staging), B = enc fp32 (cvt in-loop)
// 2 MFMAs per tile: Ah*B + Al*B
// ---------------------------------------------------------------------------
#define SBM 128
#define SBN 128
#define SBK 32

__global__ __launch_bounds__(256) void gemm_score_kernel(
    const _Float16* __restrict__ A_h, const _Float16* __restrict__ A_l,
    const float* __restrict__ Bf, float* __restrict__ C)
{
  __shared__ _Float16 sAh[SBM * SBK];   // 8 KB, rows of 64 B, unpadded (glld)
  __shared__ _Float16 sAl[SBM * SBK];   // 8 KB
  __shared__ _Float16 sB [SBN * SBK];   // 8 KB

  const int bz = blockIdx.z;
  const int m0 = blockIdx.y * SBM;
  const int n0 = blockIdx.x * SBN;
  const _Float16* Ahb = A_h + (long long)bz * TQ_ * D_ + (long long)m0 * D_;
  const _Float16* Alb = A_l + (long long)bz * TQ_ * D_ + (long long)m0 * D_;
  const float*    Bb  = Bf  + (long long)bz * TK_ * D_ + (long long)n0 * D_;

  const int t    = threadIdx.x;
  const int lane = t & 63;
  const int wave = t >> 6;
  const int wr   = (wave >> 1) * 64;
  const int wc   = (wave & 1) * 64;
  const int ln   = lane & 15;
  const int qd   = lane >> 4;

  f32x4 acc[4][4];
  #pragma unroll
  for (int i = 0; i < 4; ++i)
    #pragma unroll
    for (int j = 0; j < 4; ++j) { f32x4 z = {0.f,0.f,0.f,0.f}; acc[i][j] = z; }

  // glld A mapping: wave handles chunks {2w, 2w+1} of each plane.
  // chunk c covers rows [16c,16c+16); lane l -> row 16c + (l>>2), byte (l&3)*16;
  // LDS dest = plane + c*1024 + l*16 (contiguous in lane order).
  const int c0   = wave * 2;
  const int arow = c0 * 16 + (lane >> 2);
  const int ab   = (lane & 3) * 16;
  const char* gAh = (const char*)Ahb + (long long)arow * D_ * 2 + ab;
  const char* gAl = (const char*)Alb + (long long)arow * D_ * 2 + ab;
  const long long rstep = (long long)16 * D_ * 2;   // +16 rows
  char* lAh = (char*)sAh + c0 * 1024 + lane * 16;
  char* lAl = (char*)sAl + c0 * 1024 + lane * 16;

  // B staging: thread t -> row t>>1, half t&1 (16 floats)
  const int brow = t >> 1;
  const int bhf  = t & 1;
  const float* srcB = Bb + (long long)brow * D_ + bhf * 16;
  _Float16* dB = &sB[brow * SBK + bhf * 16];

  for (int k0 = 0; k0 < D_; k0 += SBK) {
    glld16(gAh + (long long)k0 * 2, lAh);
    glld16(gAh + (long long)k0 * 2 + rstep, lAh + 1024);
    glld16(gAl + (long long)k0 * 2, lAl);
    glld16(gAl + (long long)k0 * 2 + rstep, lAl + 1024);
    {
      __align__(16) _Float16 hb[16];
      #pragma unroll
      for (int i = 0; i < 16; i += 4) {
        float4 v = *(const float4*)(srcB + k0 + i);
        hb[i+0] = (_Float16)v.x;
        hb[i+1] = (_Float16)v.y;
        hb[i+2] = (_Float16)v.z;
        hb[i+3] = (_Float16)v.w;
      }
      ((uint4*)dB)[0] = ((const uint4*)hb)[0];
      ((uint4*)dB)[1] = ((const uint4*)hb)[1];
    }
    __syncthreads();

    f16x8 fah[4], fal[4], fb[4];
    #pragma unroll
    for (int i = 0; i < 4; ++i) {
      int ra = (wr + i * 16 + ln) * SBK + qd * 8;
      int rb = (wc + i * 16 + ln) * SBK + qd * 8;
      fah[i] = *(const f16x8*)&sAh[ra];
      fal[i] = *(const f16x8*)&sAl[ra];
      fb[i]  = *(const f16x8*)&sB[rb];
    }
    #pragma unroll
    for (int i = 0; i < 4; ++i)
      #pragma unroll
      for (int j = 0; j < 4; ++j) {
        acc[i][j] = __builtin_amdgcn_mfma_f32_16x16x32_f16(fah[i], fb[j], acc[i][j], 0, 0, 0);
        acc[i][j] = __builtin_amdgcn_mfma_f32_16x16x32_f16(fal[i], fb[j], acc[i][j], 0, 0, 0);
      }
    __syncthreads();
  }

  float* Cb = C + (long long)bz * TQ_ * TK_;
  #pragma unroll
  for (int i = 0; i < 4; ++i)
    #pragma unroll
    for (int j = 0; j < 4; ++j)
      #pragma unroll
      for (int rg = 0; rg < 4; ++rg) {
        int row = m0 + wr + i * 16 + qd * 4 + rg;
        int col = n0 + wc + j * 16 + ln;
        Cb[(long long)row * TK_ + col] = acc[i][j][rg];
      }
}

// ---------------------------------------------------------------------------
// Row softmax in place: P is [B*TQ, TK] fp32
// ---------------------------------------------------------------------------
__global__ __launch_bounds__(256) void softmax_kernel(float* __restrict__ P)
{
  __shared__ float red[8];
  float* p = P + (long long)blockIdx.x * TK_;
  const int t    = threadIdx.x;
  const int lane = t & 63;
  const int wave = t >> 6;

  float4 v[4];
  float mx = -3.0e38f;
  #pragma unroll
  for (int i = 0; i < 4; ++i) {
    v[i] = *(const float4*)&p[i * 1024 + t * 4];
    mx = fmaxf(mx, fmaxf(fmaxf(v[i].x, v[i].y), fmaxf(v[i].z, v[i].w)));
  }
  #pragma unroll
  for (int o = 32; o > 0; o >>= 1) mx = fmaxf(mx, __shfl_xor(mx, o, 64));
  if (lane == 0) red[wave] = mx;
  __syncthreads();
  mx = fmaxf(fmaxf(red[0], red[1]), fmaxf(red[2], red[3]));

  float s = 0.f;
  #pragma unroll
  for (int i = 0; i < 4; ++i) {
    v[i].x = __expf(v[i].x - mx);
    v[i].y = __expf(v[i].y - mx);
    v[i].z = __expf(v[i].z - mx);
    v[i].w = __expf(v[i].w - mx);
    s += (v[i].x + v[i].y) + (v[i].z + v[i].w);
  }
  #pragma unroll
  for (int o = 32; o > 0; o >>= 1) s += __shfl_xor(s, o, 64);
  if (lane == 0) red[4 + wave] = s;
  __syncthreads();
  s = (red[4] + red[5]) + (red[6] + red[7]);
  const float inv = 1.0f / s;

  #pragma unroll
  for (int i = 0; i < 4; ++i) {
    v[i].x *= inv; v[i].y *= inv; v[i].z *= inv; v[i].w *= inv;
    *(float4*)&p[i * 1024 + t * 4] = v[i];
  }
}

// ---------------------------------------------------------------------------
// Context GEMM: C[b][q][d] = sum_k P[b,q,k] * encT[b,d,k]
// BM=64, BN=256, 512 threads (8 waves, 2x4), B via glld, A cvt in-loop
// ---------------------------------------------------------------------------
#define CBM 64
#define CBN 256
#define CBK 32

__global__ __launch_bounds__(512) void gemm_ctx_kernel(
    const float* __restrict__ P, const _Float16* __restrict__ ET,
    float* __restrict__ C)
{
  __shared__ _Float16 sA[CBM * CBK];   // 4 KB
  __shared__ _Float16 sB[CBN * CBK];   // 16 KB (glld, unpadded)

  const int bz = blockIdx.z;
  const int m0 = blockIdx.y * CBM;
  const int n0 = blockIdx.x * CBN;
  const float*    Pb = P  + (long long)bz * TQ_ * TK_ + (long long)m0 * TK_;
  const _Float16* Eb = ET + (long long)bz * D_ * TK_  + (long long)n0 * TK_;

  const int t    = threadIdx.x;
  const int lane = t & 63;
  const int wave = t >> 6;
  const int wr   = (wave >> 2) * 32;   // 0,32
  const int wc   = (wave & 3) * 64;    // 0,64,128,192
  const int ln   = lane & 15;
  const int qd   = lane >> 4;

  f32x4 acc[2][4];
  #pragma unroll
  for (int i = 0; i < 2; ++i)
    #pragma unroll
    for (int j = 0; j < 4; ++j) { f32x4 z = {0.f,0.f,0.f,0.f}; acc[i][j] = z; }

  // glld B: 16 chunks of 1 KB; wave handles {2w, 2w+1}
  const int c0   = wave * 2;
  const int brow = c0 * 16 + (lane >> 2);
  const int bb   = (lane & 3) * 16;
  const char* gB = (const char*)Eb + (long long)brow * TK_ * 2 + bb;
  const long long rstep = (long long)16 * TK_ * 2;
  char* lB = (char*)sB + c0 * 1024 + lane * 16;

  // A: thread -> row t>>3 (0..63), seg t&7 (4 floats)
  const int arow = t >> 3;
  const int aseg = t & 7;
  const float* gA = Pb + (long long)arow * TK_ + aseg * 4;
  _Float16* lA = &sA[arow * CBK + aseg * 4];

  for (int k0 = 0; k0 < TK_; k0 += CBK) {
    glld16(gB + (long long)k0 * 2, lB);
    glld16(gB + (long long)k0 * 2 + rstep, lB + 1024);
    {
      float4 v = *(const float4*)(gA + k0);
      union { _Float16 h[4]; uint2 u; } pk;
      pk.h[0] = (_Float16)v.x;
      pk.h[1] = (_Float16)v.y;
      pk.h[2] = (_Float16)v.z;
      pk.h[3] = (_Float16)v.w;
      *(uint2*)lA = pk.u;
    }
    __syncthreads();

    f16x8 fa[2], fb[4];
    #pragma unroll
    for (int i = 0; i < 2; ++i)
      fa[i] = *(const f16x8*)&sA[(wr + i * 16 + ln) * CBK + qd * 8];
    #pragma unroll
    for (int j = 0; j < 4; ++j)
      fb[j] = *(const f16x8*)&sB[(wc + j * 16 + ln) * CBK + qd * 8];
    #pragma unroll
    for (int i = 0; i < 2; ++i)
      #pragma unroll
      for (int j = 0; j < 4; ++j)
        acc[i][j] = __builtin_amdgcn_mfma_f32_16x16x32_f16(fa[i], fb[j], acc[i][j], 0, 0, 0);
    __syncthreads();
  }

  float* Cb = C + (long long)bz * TQ_ * D_;
  #pragma unroll
  for (int i = 0; i < 2; ++i)
    #pragma unroll
    for (int j = 0; j < 4; ++j)
      #pragma unroll
      for (int rg = 0; rg < 4; ++rg) {
        int row = m0 + wr + i * 16 + qd * 4 + rg;
        int col = n0 + wc + j * 16 + ln;
        Cb[(long long)row * D_ + col] = acc[i][j][rg];
      }
}

// ---------------------------------------------------------------------------
extern "C" void kernel_launch(void* const* d_in, const int* in_sizes, int n_in,
                              void* d_out, int out_size, void* d_ws, size_t ws_size,
                              hipStream_t stream) {
  (void)in_sizes; (void)n_in; (void)out_size; (void)ws_size;
  const float* dec = (const float*)d_in[0];   // [16,1024,512]
  const float* enc = (const float*)d_in[1];   // [16,4096,512]
  const float* Wa  = (const float*)d_in[2];   // [512,512]
  // b_a constant along softmax axis -> cancels exactly; unused.

  float* ctx   = (float*)d_out;                                   // [16,1024,512]
  float* align = ctx + (long long)B_ * TQ_ * D_;                  // [16,1024,4096]

  _Float16* dec2h = (_Float16*)d_ws;                              // 16.78 MB
  _Float16* dec2l = dec2h + (size_t)B_ * TQ_ * D_;                // 16.78 MB
  _Float16* encT  = dec2l + (size_t)B_ * TQ_ * D_;                // 67.1 MB

  // 1) encT[b][d][k] = f16(enc[b][k][d])
  transpose_conv_kernel<<<dim3(TK_ / 64, D_ / 64, B_), 256, 0, stream>>>(enc, encT);

  // 2) dec2 = dec @ W^T (split-bf16 triple), epilogue -> f16 hi/lo planes
  gemm_dec2_kernel<<<dim3(D_ / DBN, (B_ * TQ_) / DBM, 1), 256, 0, stream>>>(
      dec, Wa, dec2h, dec2l);

  // 3) score = dec2 @ enc^T (f16: Ah*B + Al*B)
  gemm_score_kernel<<<dim3(TK_ / SBN, TQ_ / SBM, B_), 256, 0, stream>>>(
      dec2h, dec2l, enc, align);

  // 4) softmax rows in place
  softmax_kernel<<<B_ * TQ_, 256, 0, stream>>>(align);

  // 5) ctx = P @ encT^T (f16)
  gemm_ctx_kernel<<<dim3(D_ / CBN, TQ_ / CBM, B_), 512, 0, stream>>>(align, encT, ctx);
}